// Round 8
// baseline (165.918 us; speedup 1.0000x reference)
//
#include <hip/hip_runtime.h>
#include <math.h>

#define NH 16
#define HD 64
#define SEQ 2048
#define BAT 2
#define EMB 1024
#define MTOT (BAT*SEQ)   // 4096
#define NTOT (3*EMB)     // 3072

typedef __attribute__((ext_vector_type(8))) short bf16x8;
typedef __attribute__((ext_vector_type(4))) float f32x4;

#define MFMA16(a,b,c) __builtin_amdgcn_mfma_f32_16x16x32_bf16(a,b,c,0,0,0)

__device__ inline short f2bf(float f) {
    union { float f; unsigned u; } x; x.f = f;
    unsigned r = (x.u + 0x7FFF + ((x.u >> 16) & 1)) >> 16;
    return (short)r;
}

// raw v_exp_f32 (inputs bounded to [-12,12]: no range/denorm handling needed)
__device__ inline float fast_exp2(float x) {
#if __has_builtin(__builtin_amdgcn_exp2f)
    return __builtin_amdgcn_exp2f(x);
#else
    float r; asm("v_exp_f32 %0, %1" : "=v"(r) : "v"(x)); return r;
#endif
}

// pack two f32 -> bf16x2 by TRUNCATION: single v_perm (P-weights; bias
// cancels in O/l ratio since l uses the same truncated P)
__device__ inline unsigned pack2bf_t(float a, float b) {
    union { float f; unsigned u; } x, y; x.f = a; y.f = b;
    return __builtin_amdgcn_perm(y.u, x.u, 0x07060302u);
}

typedef const __attribute__((address_space(1))) void* gp_t;
typedef __attribute__((address_space(3))) void* lp_t;
// async global->LDS, 16B/lane; LDS dest = wave-uniform base + lane*16
__device__ inline void gload16(const void* g, void* l) {
    __builtin_amdgcn_global_load_lds((gp_t)(uintptr_t)g, (lp_t)(uintptr_t)l, 16, 0, 0);
}

// ---------------------------------------------------------------------------
// Prep: f32 -> bf16 for X (4M) and Wq|Wk|Wv (3M) into scratch carved from d_out.
// ---------------------------------------------------------------------------
__global__ __launch_bounds__(256) void prep_kernel(
    const float* __restrict__ x, const float* __restrict__ wq,
    const float* __restrict__ wk, const float* __restrict__ wv,
    short* __restrict__ xb, short* __restrict__ wb)
{
    const size_t NX = (size_t)MTOT * EMB;
    const size_t NW = (size_t)EMB * EMB;
    const size_t i4 = ((size_t)blockIdx.x * 256 + threadIdx.x) * 4;
    float4 v; short* dst;
    if (i4 < NX) { v = *(const float4*)(x + i4); dst = xb + i4; }
    else {
        size_t j = i4 - NX;
        const float* s = (j < NW) ? wq : (j < 2 * NW) ? wk : wv;
        v = *(const float4*)(s + (j & (NW - 1)));
        dst = wb + j;
    }
    short4 o; o.x = f2bf(v.x); o.y = f2bf(v.y); o.z = f2bf(v.z); o.w = f2bf(v.w);
    *(short4*)dst = o;
}

// ---------------------------------------------------------------------------
// Fused QKV GEMM (m97 structure): 128x128 tile, BK=64, global_load_lds w=16,
// XOR-swizzled LDS, plain 2-D grid.
// NEW: epilogue goes through LDS (reusing As/Bs as a 128x128 bf16 tile with
// 16B-granule XOR swizzle) so all global stores are coalesced 16B:
//   Q/K: l2norm scale -> T[s][c] -> row-contiguous stores to [bh][s][d]
//   V:   T rows written at pos-permuted s -> transposed read -> contiguous
//        128 B/row stores to vperm[bh][d][pos]
// ---------------------------------------------------------------------------
__global__ __launch_bounds__(256) void qkv_gemm_fast(
    const short* __restrict__ xb, const short* __restrict__ wb,
    short* __restrict__ qws, short* __restrict__ kws, short* __restrict__ vperm,
    const float* __restrict__ gptr)
{
    __shared__ short smem[2 * 128 * 64];   // As | Bs, reused as T[128][128]
    short* As = smem;
    short* Bs = smem + 128 * 64;
    const int m0 = blockIdx.x * 128, n0 = blockIdx.y * 128;
    const int t = threadIdx.x, wave = t >> 6, lane = t & 63;
    const int quad = lane >> 4, l16 = lane & 15;
    const int wm = (wave & 1) * 64, wn = (wave >> 1) * 64;

    // staging decode: instr j covers LDS rows wave*32+j*8 .. +7
    const int srow = wave * 32 + (lane >> 3);
    const int scol = ((lane & 7) ^ (srow & 7)) * 8;
    const short* ga = xb + (size_t)(m0 + srow) * EMB + scol;
    const short* gb = wb + (size_t)(n0 + srow) * EMB + scol;
    short* lA = As + (size_t)wave * 2048;
    short* lB = Bs + (size_t)wave * 2048;

    const short* Aa[2]; const short* Ba[2];
#pragma unroll
    for (int ks = 0; ks < 2; ++ks) {
        const int pc = (ks * 32 + quad * 8) ^ ((l16 & 7) * 8);
        Aa[ks] = As + (wm + l16) * 64 + pc;
        Ba[ks] = Bs + (wn + l16) * 64 + pc;
    }

    f32x4 acc[4][4] = {};

    for (int k0 = 0; k0 < EMB; k0 += 64) {
#pragma unroll
        for (int j = 0; j < 4; ++j) {
            gload16(ga + k0 + (size_t)j * 8 * EMB, lA + j * 512);
            gload16(gb + k0 + (size_t)j * 8 * EMB, lB + j * 512);
        }
        __syncthreads();
#pragma unroll
        for (int ks = 0; ks < 2; ++ks) {
            bf16x8 af[4], bfr[4];
#pragma unroll
            for (int i = 0; i < 4; ++i) af[i]  = *(const bf16x8*)(Aa[ks] + i * 1024);
#pragma unroll
            for (int i = 0; i < 4; ++i) bfr[i] = *(const bf16x8*)(Ba[ks] + i * 1024);
#pragma unroll
            for (int mf = 0; mf < 4; ++mf)
#pragma unroll
                for (int nf = 0; nf < 4; ++nf)
                    acc[mf][nf] = MFMA16(af[mf], bfr[nf], acc[mf][nf]);
        }
        __syncthreads();
    }

    // ---- epilogue (through LDS, coalesced stores) ----
    short* T = smem;   // 128 rows x 128 cols bf16, 16B-granule XOR swizzle
    const int mat = n0 >> 10;   // 0=Q,1=K,2=V (block-uniform)

    if (mat < 2) {
        const float scale = (mat == 0) ? gptr[0] * 1.4426950408889634f : 1.0f;
        float inv[4][4];
#pragma unroll
        for (int mf = 0; mf < 4; ++mf)
#pragma unroll
            for (int reg = 0; reg < 4; ++reg) {
                float ss = 0.f;
#pragma unroll
                for (int nf = 0; nf < 4; ++nf) { float v = acc[mf][nf][reg]; ss += v * v; }
                ss += __shfl_xor(ss, 1, 16);
                ss += __shfl_xor(ss, 2, 16);
                ss += __shfl_xor(ss, 4, 16);
                ss += __shfl_xor(ss, 8, 16);
                inv[mf][reg] = scale / fmaxf(sqrtf(ss), 1e-12f);
            }
#pragma unroll
        for (int mf = 0; mf < 4; ++mf)
#pragma unroll
            for (int nf = 0; nf < 4; ++nf) {
                const int c = wn + nf * 16 + l16;
#pragma unroll
                for (int reg = 0; reg < 4; ++reg) {
                    const int s = wm + mf * 16 + quad * 4 + reg;
                    T[s * 128 + (((c >> 3) ^ (s & 15)) << 3) + (c & 7)] =
                        f2bf(acc[mf][nf][reg] * inv[mf][reg]);
                }
            }
        __syncthreads();
        short* outp = (mat == 0) ? qws : kws;
        const int r = t >> 1, half = t & 1;
        const int sg = m0 + r, bb = sg >> 11, sl = sg & (SEQ - 1);
        const int h = ((n0 & 1023) >> 6) + half;
        short* orow = outp + ((size_t)(bb * NH + h) * SEQ + sl) * HD;
#pragma unroll
        for (int j = 0; j < 8; ++j) {
            int4 v = *(const int4*)&T[r * 128 + ((((half * 8 + j)) ^ (r & 15)) << 3)];
            *(int4*)&orow[j * 8] = v;
        }
    } else {
        // V: write rows at pos-permuted s, read transposed, store contiguous
#pragma unroll
        for (int mf = 0; mf < 4; ++mf)
#pragma unroll
            for (int nf = 0; nf < 4; ++nf) {
                const int c = wn + nf * 16 + l16;
#pragma unroll
                for (int reg = 0; reg < 4; ++reg) {
                    const int s = wm + mf * 16 + quad * 4 + reg;
                    const int sp = (s & ~31) + ((s & 12) >> 2) * 8 + ((s >> 4) & 1) * 4 + (s & 3);
                    T[sp * 128 + (((c >> 3) ^ (sp & 15)) << 3) + (c & 7)] =
                        f2bf(acc[mf][nf][reg]);
                }
            }
        __syncthreads();
        const int c = t >> 1, half = t & 1;
        const int h = ((n0 & 1023) >> 6) + (c >> 6), d = c & 63;
        const int bb = m0 >> 11, p0 = (m0 & (SEQ - 1)) + half * 64;
        short* vrow = vperm + ((size_t)(bb * NH + h) * HD + d) * SEQ + p0;
        const int cg = c >> 3, ce = c & 7;
#pragma unroll
        for (int j = 0; j < 8; ++j) {
            union { int4 v; short s[8]; } tmp;
#pragma unroll
            for (int e = 0; e < 8; ++e) {
                const int s = half * 64 + j * 8 + e;
                tmp.s[e] = T[s * 128 + ((cg ^ (s & 15)) << 3) + ce];
            }
            *(int4*)&vrow[j * 8] = tmp.v;
        }
    }
}

// ---------------------------------------------------------------------------
// Attention, wave-specialized over keys: block = 64 q; wave (qh,kh) computes
// q-half qh (32 q) x key-strip kh (32 of each 64-key tile). K staged by qh=0
// waves, V by qh=1 waves; double-buffered; 2-way-max swizzles. S^T trick:
// P exits QK^T MFMA directly in PV A-operand layout. l via ones-MFMA.
// Truncating bf16 pack (1 v_perm). Partial O/l reduced across kh through LDS.
// Grid 1024; bh = (id&7)*4 + ((id>>3)&3) -> each XCD's L2 holds 4 bh's K/V.
// ---------------------------------------------------------------------------
__global__ __launch_bounds__(256, 4) void attn_kernel(
    const short* __restrict__ qws, const short* __restrict__ kws,
    const short* __restrict__ vperm, float* __restrict__ out)
{
    __shared__ short Kt[2][2][2048];   // [buf][kh][klocal*64 + dgrp_phys*8]
    __shared__ short Vt[2][2][2048];   // [buf][kh][d*32 + ug_phys*8]
    __shared__ float lbuf[64];

    const int id = blockIdx.x;
    const int bh = (id & 7) * 4 + ((id >> 3) & 3);
    const int qt = id >> 5;                        // 0..31
    const int b = bh >> 4, h = bh & (NH - 1);
    const size_t base = (size_t)bh * SEQ * HD;
    const int t = threadIdx.x, wave = t >> 6, lane = t & 63;
    const int quad = lane >> 4, l16 = lane & 15;
    const int qh = wave >> 1, kh = wave & 1;

    // Q B-frags (q = qt*64 + qh*32 + qsub*16 + l16), loaded once
    bf16x8 bq[2][2];
#pragma unroll
    for (int qsub = 0; qsub < 2; ++qsub) {
        const short* qp = qws + base +
            (size_t)(qt * 64 + qh * 32 + qsub * 16 + l16) * HD + quad * 8;
        bq[qsub][0] = *(const bf16x8*)(qp);
        bq[qsub][1] = *(const bf16x8*)(qp + 32);
    }
    bf16x8 ones;
#pragma unroll
    for (int i = 0; i < 8; ++i) ones[i] = (short)0x3F80;

    // frag read offsets (shorts, within this wave's kh region)
    int koff[2][2];   // [msub][ks]: K A-frag, key=msub*16+l16, d=ks*32+quad*8
#pragma unroll
    for (int msub = 0; msub < 2; ++msub)
#pragma unroll
        for (int ks = 0; ks < 2; ++ks)
            koff[msub][ks] = (msub * 16 + l16) * 64 + (((ks * 4 + quad) ^ (l16 & 7)) * 8);
    int voff[4];      // V B-frag: d=nt*16+l16, slot group = quad (phys ^ (d>>1)&3)
#pragma unroll
    for (int nt = 0; nt < 4; ++nt) {
        const int d = nt * 16 + l16;
        voff[nt] = d * 32 + ((quad ^ ((d >> 1) & 3)) * 8);
    }

    f32x4 o_acc[2][4] = {};   // [qsub][nt]
    f32x4 l_acc[2] = {};

    // stage tile tt (this wave's kh strip only) into buffer p
    auto stage = [&](int tt, int p) {
        if (qh == 0) {  // K strip: [32 keys][64 d], 4 gload16
#pragma unroll
            for (int j = 0; j < 4; ++j) {
                const int kl = j * 8 + (lane >> 3);
                const int row = tt * 64 + kh * 32 + kl;
                gload16(kws + base + (size_t)row * HD + (((lane & 7) ^ (kl & 7)) * 8),
                        &Kt[p][kh][j * 512 + lane * 8]);
            }
        } else {        // V strip: [64 d][32 slots], 4 gload16
#pragma unroll
            for (int j = 0; j < 4; ++j) {
                const int d = j * 16 + (lane >> 2);
                const int ug = (lane & 3) ^ ((d >> 1) & 3);
                gload16(vperm + base + (size_t)d * SEQ + tt * 64 + kh * 32 + ug * 8,
                        &Vt[p][kh][j * 512 + lane * 8]);
            }
        }
    };

    stage(0, 0);
    __syncthreads();   // tile 0 resident

    for (int tt = 0; tt < SEQ / 64; ++tt) {
        const int p = tt & 1;
        if (tt + 1 < SEQ / 64) stage(tt + 1, p ^ 1);   // prefetch overlaps compute
        const short* Kp = &Kt[p][kh][0];
        const short* Vp = &Vt[p][kh][0];

        // S^T: 32 keys (this strip) x 32 q (this half)
        f32x4 st[2][2];   // [msub][qsub]
#pragma unroll
        for (int msub = 0; msub < 2; ++msub) {
            bf16x8 a0 = *(const bf16x8*)(Kp + koff[msub][0]);
            bf16x8 a1 = *(const bf16x8*)(Kp + koff[msub][1]);
#pragma unroll
            for (int qsub = 0; qsub < 2; ++qsub) {
                f32x4 z = {};
                z = MFMA16(a0, bq[qsub][0], z);
                st[msub][qsub] = MFMA16(a1, bq[qsub][1], z);
            }
        }
        // V B-frags (shared across qsub)
        bf16x8 vf[4];
#pragma unroll
        for (int nt = 0; nt < 4; ++nt)
            vf[nt] = *(const bf16x8*)(Vp + voff[nt]);
        // exp + truncating pack -> P A-frag; l + O MFMAs
#pragma unroll
        for (int qsub = 0; qsub < 2; ++qsub) {
            bf16x8 pa;
            unsigned* pu = (unsigned*)&pa;
            pu[0] = pack2bf_t(fast_exp2(st[0][qsub][0]), fast_exp2(st[0][qsub][1]));
            pu[1] = pack2bf_t(fast_exp2(st[0][qsub][2]), fast_exp2(st[0][qsub][3]));
            pu[2] = pack2bf_t(fast_exp2(st[1][qsub][0]), fast_exp2(st[1][qsub][1]));
            pu[3] = pack2bf_t(fast_exp2(st[1][qsub][2]), fast_exp2(st[1][qsub][3]));
            l_acc[qsub] = MFMA16(pa, ones, l_acc[qsub]);
#pragma unroll
            for (int nt = 0; nt < 4; ++nt)
                o_acc[qsub][nt] = MFMA16(pa, vf[nt], o_acc[qsub][nt]);
        }
        __syncthreads();   // drains prefetch (after compute) + guards buffer reuse
    }

    // ---- cross-kh reduction (reuse Kt as 16 KB float buffer) ----
    float* red = (float*)&Kt[0][0][0];   // [qh][q_local 32][d 64]
    if (kh == 1) {
#pragma unroll
        for (int qsub = 0; qsub < 2; ++qsub) {
#pragma unroll
            for (int nt = 0; nt < 4; ++nt)
#pragma unroll
                for (int r = 0; r < 4; ++r)
                    red[qh * 2048 + (qsub * 16 + quad * 4 + r) * 64 + nt * 16 + l16] =
                        o_acc[qsub][nt][r];
            if (l16 == 0)
#pragma unroll
                for (int r = 0; r < 4; ++r)
                    lbuf[qh * 32 + qsub * 16 + quad * 4 + r] = l_acc[qsub][r];
        }
    }
    __syncthreads();
    if (kh == 0) {
#pragma unroll
        for (int qsub = 0; qsub < 2; ++qsub) {
            float linv[4];
#pragma unroll
            for (int r = 0; r < 4; ++r)
                linv[r] = 1.0f / (l_acc[qsub][r] + lbuf[qh * 32 + qsub * 16 + quad * 4 + r]);
            const int s = qt * 64 + qh * 32 + qsub * 16 + quad * 4;
            float* ob = out + ((size_t)b * SEQ + s) * EMB + h * HD + l16;
#pragma unroll
            for (int nt = 0; nt < 4; ++nt)
#pragma unroll
                for (int r = 0; r < 4; ++r) {
                    const float o = o_acc[qsub][nt][r] +
                        red[qh * 2048 + (qsub * 16 + quad * 4 + r) * 64 + nt * 16 + l16];
                    ob[(size_t)r * EMB + nt * 16] = o * linv[r];
                }
        }
    }
}

extern "C" void kernel_launch(void* const* d_in, const int* in_sizes, int n_in,
                              void* d_out, int out_size, void* d_ws, size_t ws_size,
                              hipStream_t stream) {
    (void)in_sizes; (void)n_in; (void)out_size; (void)ws_size;
    const float* x  = (const float*)d_in[0];
    const float* Wq = (const float*)d_in[1];
    const float* Wk = (const float*)d_in[2];
    const float* Wv = (const float*)d_in[3];
    const float* g  = (const float*)d_in[4];
    float* out = (float*)d_out;

    const size_t per = (size_t)BAT * NH * SEQ * HD;   // 4,194,304 elems
    short* qws   = (short*)d_ws;
    short* kws   = qws + per;
    short* vperm = kws + per;                          // ws: 25.2 MB total

    // bf16 staging lives in d_out (16.8 MB; attn fully overwrites it last)
    short* xb = (short*)out;                           // 4M shorts
    short* wb = xb + (size_t)MTOT * EMB;               // 3M shorts (7M <= 8.38M cap)

    prep_kernel<<<7168, 256, 0, stream>>>(x, Wq, Wk, Wv, xb, wb);
    qkv_gemm_fast<<<dim3(MTOT / 128, NTOT / 128), 256, 0, stream>>>(
        xb, wb, qws, kws, vperm, g);
    attn_kernel<<<(SEQ / 64) * BAT * NH, 256, 0, stream>>>(qws, kws, vperm, out);
}

// Round 9
// 161.620 us; speedup vs baseline: 1.0266x; 1.0266x over previous
//
#include <hip/hip_runtime.h>
#include <math.h>

#define NH 16
#define HD 64
#define SEQ 2048
#define BAT 2
#define EMB 1024
#define MTOT (BAT*SEQ)   // 4096
#define NTOT (3*EMB)     // 3072

typedef __attribute__((ext_vector_type(8))) short bf16x8;
typedef __attribute__((ext_vector_type(4))) float f32x4;

#define MFMA16(a,b,c) __builtin_amdgcn_mfma_f32_16x16x32_bf16(a,b,c,0,0,0)

__device__ inline short f2bf(float f) {
    union { float f; unsigned u; } x; x.f = f;
    unsigned r = (x.u + 0x7FFF + ((x.u >> 16) & 1)) >> 16;
    return (short)r;
}

// raw v_exp_f32 (inputs bounded to [-12,12]: no range/denorm handling needed)
__device__ inline float fast_exp2(float x) {
#if __has_builtin(__builtin_amdgcn_exp2f)
    return __builtin_amdgcn_exp2f(x);
#else
    float r; asm("v_exp_f32 %0, %1" : "=v"(r) : "v"(x)); return r;
#endif
}

// pack two f32 -> bf16x2 by TRUNCATION: single v_perm (P-weights; bias
// cancels in O/l ratio since l uses the same truncated P)
__device__ inline unsigned pack2bf_t(float a, float b) {
    union { float f; unsigned u; } x, y; x.f = a; y.f = b;
    return __builtin_amdgcn_perm(y.u, x.u, 0x07060302u);
}

typedef const __attribute__((address_space(1))) void* gp_t;
typedef __attribute__((address_space(3))) void* lp_t;
// async global->LDS, 16B/lane; LDS dest = wave-uniform base + lane*16
__device__ inline void gload16(const void* g, void* l) {
    __builtin_amdgcn_global_load_lds((gp_t)(uintptr_t)g, (lp_t)(uintptr_t)l, 16, 0, 0);
}

// ---------------------------------------------------------------------------
// Prep: f32 -> bf16 for X (4M) and Wq|Wk|Wv (3M) into scratch carved from d_out.
// ---------------------------------------------------------------------------
__global__ __launch_bounds__(256) void prep_kernel(
    const float* __restrict__ x, const float* __restrict__ wq,
    const float* __restrict__ wk, const float* __restrict__ wv,
    short* __restrict__ xb, short* __restrict__ wb)
{
    const size_t NX = (size_t)MTOT * EMB;
    const size_t NW = (size_t)EMB * EMB;
    const size_t i4 = ((size_t)blockIdx.x * 256 + threadIdx.x) * 4;
    float4 v; short* dst;
    if (i4 < NX) { v = *(const float4*)(x + i4); dst = xb + i4; }
    else {
        size_t j = i4 - NX;
        const float* s = (j < NW) ? wq : (j < 2 * NW) ? wk : wv;
        v = *(const float4*)(s + (j & (NW - 1)));
        dst = wb + j;
    }
    short4 o; o.x = f2bf(v.x); o.y = f2bf(v.y); o.z = f2bf(v.z); o.w = f2bf(v.w);
    *(short4*)dst = o;
}

// ---------------------------------------------------------------------------
// Fused QKV GEMM: 128x128 tile, BK=64, global_load_lds w=16, XOR-swizzled
// LDS, NOW DOUBLE-BUFFERED (stage k+1 during compute k, single barrier/iter
// -> the vmcnt drain at the barrier lands after compute instead of
// serializing with it; this was the attn kernel's pattern, gemm had the
// naive 2-barrier m97 loop). LDS 2x32KB = 64 KB.
// Epilogue through LDS (coalesced 16B stores), reusing buffer space.
// ---------------------------------------------------------------------------
__global__ __launch_bounds__(256) void qkv_gemm_fast(
    const short* __restrict__ xb, const short* __restrict__ wb,
    short* __restrict__ qws, short* __restrict__ kws, short* __restrict__ vperm,
    const float* __restrict__ gptr)
{
    __shared__ short smem[2 * 2 * 128 * 64];   // [buf][As|Bs]; reused as T[128][128]
    const int m0 = blockIdx.x * 128, n0 = blockIdx.y * 128;
    const int t = threadIdx.x, wave = t >> 6, lane = t & 63;
    const int quad = lane >> 4, l16 = lane & 15;
    const int wm = (wave & 1) * 64, wn = (wave >> 1) * 64;

    // staging decode: instr j covers LDS rows wave*32+j*8 .. +7
    const int srow = wave * 32 + (lane >> 3);
    const int scol = ((lane & 7) ^ (srow & 7)) * 8;
    const short* ga = xb + (size_t)(m0 + srow) * EMB + scol;
    const short* gb = wb + (size_t)(n0 + srow) * EMB + scol;

    // frag read offsets (buffer-relative, shorts)
    int aoff[2], boff[2];
#pragma unroll
    for (int ks = 0; ks < 2; ++ks) {
        const int pc = (ks * 32 + quad * 8) ^ ((l16 & 7) * 8);
        aoff[ks] = (wm + l16) * 64 + pc;
        boff[ks] = 8192 + (wn + l16) * 64 + pc;
    }

    f32x4 acc[4][4] = {};

    // stage K-step k0 into buffer p (16 KB A + 16 KB B)
    auto stageg = [&](int k0, int p) {
        short* lA = smem + p * 16384 + wave * 2048;
        short* lB = smem + p * 16384 + 8192 + wave * 2048;
#pragma unroll
        for (int j = 0; j < 4; ++j) {
            gload16(ga + k0 + (size_t)j * 8 * EMB, lA + j * 512);
            gload16(gb + k0 + (size_t)j * 8 * EMB, lB + j * 512);
        }
    };

    stageg(0, 0);
    __syncthreads();   // buffer 0 resident

    for (int it = 0; it < EMB / 64; ++it) {
        const int p = it & 1;
        if (it + 1 < EMB / 64) stageg((it + 1) * 64, p ^ 1);   // prefetch overlaps compute
        const short* base = smem + p * 16384;
#pragma unroll
        for (int ks = 0; ks < 2; ++ks) {
            bf16x8 af[4], bfr[4];
#pragma unroll
            for (int i = 0; i < 4; ++i) af[i]  = *(const bf16x8*)(base + aoff[ks] + i * 1024);
#pragma unroll
            for (int i = 0; i < 4; ++i) bfr[i] = *(const bf16x8*)(base + boff[ks] + i * 1024);
#pragma unroll
            for (int mf = 0; mf < 4; ++mf)
#pragma unroll
                for (int nf = 0; nf < 4; ++nf)
                    acc[mf][nf] = MFMA16(af[mf], bfr[nf], acc[mf][nf]);
        }
        __syncthreads();   // drains prefetch (after compute) + guards buffer reuse
    }

    // ---- epilogue (through LDS, coalesced stores) ----
    short* T = smem;   // 128 rows x 128 cols bf16, 16B-granule XOR swizzle
    const int mat = n0 >> 10;   // 0=Q,1=K,2=V (block-uniform)

    if (mat < 2) {
        const float scale = (mat == 0) ? gptr[0] * 1.4426950408889634f : 1.0f;
        float inv[4][4];
#pragma unroll
        for (int mf = 0; mf < 4; ++mf)
#pragma unroll
            for (int reg = 0; reg < 4; ++reg) {
                float ss = 0.f;
#pragma unroll
                for (int nf = 0; nf < 4; ++nf) { float v = acc[mf][nf][reg]; ss += v * v; }
                ss += __shfl_xor(ss, 1, 16);
                ss += __shfl_xor(ss, 2, 16);
                ss += __shfl_xor(ss, 4, 16);
                ss += __shfl_xor(ss, 8, 16);
                inv[mf][reg] = scale / fmaxf(sqrtf(ss), 1e-12f);
            }
#pragma unroll
        for (int mf = 0; mf < 4; ++mf)
#pragma unroll
            for (int nf = 0; nf < 4; ++nf) {
                const int c = wn + nf * 16 + l16;
#pragma unroll
                for (int reg = 0; reg < 4; ++reg) {
                    const int s = wm + mf * 16 + quad * 4 + reg;
                    T[s * 128 + (((c >> 3) ^ (s & 15)) << 3) + (c & 7)] =
                        f2bf(acc[mf][nf][reg] * inv[mf][reg]);
                }
            }
        __syncthreads();
        short* outp = (mat == 0) ? qws : kws;
        const int r = t >> 1, half = t & 1;
        const int sg = m0 + r, bb = sg >> 11, sl = sg & (SEQ - 1);
        const int h = ((n0 & 1023) >> 6) + half;
        short* orow = outp + ((size_t)(bb * NH + h) * SEQ + sl) * HD;
#pragma unroll
        for (int j = 0; j < 8; ++j) {
            int4 v = *(const int4*)&T[r * 128 + ((((half * 8 + j)) ^ (r & 15)) << 3)];
            *(int4*)&orow[j * 8] = v;
        }
    } else {
        // V: write rows at pos-permuted s, read transposed, store contiguous
#pragma unroll
        for (int mf = 0; mf < 4; ++mf)
#pragma unroll
            for (int nf = 0; nf < 4; ++nf) {
                const int c = wn + nf * 16 + l16;
#pragma unroll
                for (int reg = 0; reg < 4; ++reg) {
                    const int s = wm + mf * 16 + quad * 4 + reg;
                    const int sp = (s & ~31) + ((s & 12) >> 2) * 8 + ((s >> 4) & 1) * 4 + (s & 3);
                    T[sp * 128 + (((c >> 3) ^ (sp & 15)) << 3) + (c & 7)] =
                        f2bf(acc[mf][nf][reg]);
                }
            }
        __syncthreads();
        const int c = t >> 1, half = t & 1;
        const int h = ((n0 & 1023) >> 6) + (c >> 6), d = c & 63;
        const int bb = m0 >> 11, p0 = (m0 & (SEQ - 1)) + half * 64;
        short* vrow = vperm + ((size_t)(bb * NH + h) * HD + d) * SEQ + p0;
        const int cg = c >> 3, ce = c & 7;
#pragma unroll
        for (int j = 0; j < 8; ++j) {
            union { int4 v; short s[8]; } tmp;
#pragma unroll
            for (int e = 0; e < 8; ++e) {
                const int s = half * 64 + j * 8 + e;
                tmp.s[e] = T[s * 128 + ((cg ^ (s & 15)) << 3) + ce];
            }
            *(int4*)&vrow[j * 8] = tmp.v;
        }
    }
}

// ---------------------------------------------------------------------------
// Attention, wave-specialized over keys: block = 64 q; wave (qh,kh) computes
// q-half qh (32 q) x key-strip kh (32 of each 64-key tile). K staged by qh=0
// waves, V by qh=1 waves; double-buffered; 2-way-max swizzles. S^T trick:
// P exits QK^T MFMA directly in PV A-operand layout. l via ones-MFMA.
// Truncating bf16 pack (1 v_perm). Partial O/l reduced across kh through LDS.
// Grid 1024; bh = (id&7)*4 + ((id>>3)&3) -> each XCD's L2 holds 4 bh's K/V.
// ---------------------------------------------------------------------------
__global__ __launch_bounds__(256, 4) void attn_kernel(
    const short* __restrict__ qws, const short* __restrict__ kws,
    const short* __restrict__ vperm, float* __restrict__ out)
{
    __shared__ short Kt[2][2][2048];   // [buf][kh][klocal*64 + dgrp_phys*8]
    __shared__ short Vt[2][2][2048];   // [buf][kh][d*32 + ug_phys*8]
    __shared__ float lbuf[64];

    const int id = blockIdx.x;
    const int bh = (id & 7) * 4 + ((id >> 3) & 3);
    const int qt = id >> 5;                        // 0..31
    const int b = bh >> 4, h = bh & (NH - 1);
    const size_t base = (size_t)bh * SEQ * HD;
    const int t = threadIdx.x, wave = t >> 6, lane = t & 63;
    const int quad = lane >> 4, l16 = lane & 15;
    const int qh = wave >> 1, kh = wave & 1;

    // Q B-frags (q = qt*64 + qh*32 + qsub*16 + l16), loaded once
    bf16x8 bq[2][2];
#pragma unroll
    for (int qsub = 0; qsub < 2; ++qsub) {
        const short* qp = qws + base +
            (size_t)(qt * 64 + qh * 32 + qsub * 16 + l16) * HD + quad * 8;
        bq[qsub][0] = *(const bf16x8*)(qp);
        bq[qsub][1] = *(const bf16x8*)(qp + 32);
    }
    bf16x8 ones;
#pragma unroll
    for (int i = 0; i < 8; ++i) ones[i] = (short)0x3F80;

    // frag read offsets (shorts, within this wave's kh region)
    int koff[2][2];   // [msub][ks]: K A-frag, key=msub*16+l16, d=ks*32+quad*8
#pragma unroll
    for (int msub = 0; msub < 2; ++msub)
#pragma unroll
        for (int ks = 0; ks < 2; ++ks)
            koff[msub][ks] = (msub * 16 + l16) * 64 + (((ks * 4 + quad) ^ (l16 & 7)) * 8);
    int voff[4];      // V B-frag: d=nt*16+l16, slot group = quad (phys ^ (d>>1)&3)
#pragma unroll
    for (int nt = 0; nt < 4; ++nt) {
        const int d = nt * 16 + l16;
        voff[nt] = d * 32 + ((quad ^ ((d >> 1) & 3)) * 8);
    }

    f32x4 o_acc[2][4] = {};   // [qsub][nt]
    f32x4 l_acc[2] = {};

    // stage tile tt (this wave's kh strip only) into buffer p
    auto stage = [&](int tt, int p) {
        if (qh == 0) {  // K strip: [32 keys][64 d], 4 gload16
#pragma unroll
            for (int j = 0; j < 4; ++j) {
                const int kl = j * 8 + (lane >> 3);
                const int row = tt * 64 + kh * 32 + kl;
                gload16(kws + base + (size_t)row * HD + (((lane & 7) ^ (kl & 7)) * 8),
                        &Kt[p][kh][j * 512 + lane * 8]);
            }
        } else {        // V strip: [64 d][32 slots], 4 gload16
#pragma unroll
            for (int j = 0; j < 4; ++j) {
                const int d = j * 16 + (lane >> 2);
                const int ug = (lane & 3) ^ ((d >> 1) & 3);
                gload16(vperm + base + (size_t)d * SEQ + tt * 64 + kh * 32 + ug * 8,
                        &Vt[p][kh][j * 512 + lane * 8]);
            }
        }
    };

    stage(0, 0);
    __syncthreads();   // tile 0 resident

    for (int tt = 0; tt < SEQ / 64; ++tt) {
        const int p = tt & 1;
        if (tt + 1 < SEQ / 64) stage(tt + 1, p ^ 1);   // prefetch overlaps compute
        const short* Kp = &Kt[p][kh][0];
        const short* Vp = &Vt[p][kh][0];

        // S^T: 32 keys (this strip) x 32 q (this half)
        f32x4 st[2][2];   // [msub][qsub]
#pragma unroll
        for (int msub = 0; msub < 2; ++msub) {
            bf16x8 a0 = *(const bf16x8*)(Kp + koff[msub][0]);
            bf16x8 a1 = *(const bf16x8*)(Kp + koff[msub][1]);
#pragma unroll
            for (int qsub = 0; qsub < 2; ++qsub) {
                f32x4 z = {};
                z = MFMA16(a0, bq[qsub][0], z);
                st[msub][qsub] = MFMA16(a1, bq[qsub][1], z);
            }
        }
        // V B-frags (shared across qsub)
        bf16x8 vf[4];
#pragma unroll
        for (int nt = 0; nt < 4; ++nt)
            vf[nt] = *(const bf16x8*)(Vp + voff[nt]);
        // exp + truncating pack -> P A-frag; l + O MFMAs
#pragma unroll
        for (int qsub = 0; qsub < 2; ++qsub) {
            bf16x8 pa;
            unsigned* pu = (unsigned*)&pa;
            pu[0] = pack2bf_t(fast_exp2(st[0][qsub][0]), fast_exp2(st[0][qsub][1]));
            pu[1] = pack2bf_t(fast_exp2(st[0][qsub][2]), fast_exp2(st[0][qsub][3]));
            pu[2] = pack2bf_t(fast_exp2(st[1][qsub][0]), fast_exp2(st[1][qsub][1]));
            pu[3] = pack2bf_t(fast_exp2(st[1][qsub][2]), fast_exp2(st[1][qsub][3]));
            l_acc[qsub] = MFMA16(pa, ones, l_acc[qsub]);
#pragma unroll
            for (int nt = 0; nt < 4; ++nt)
                o_acc[qsub][nt] = MFMA16(pa, vf[nt], o_acc[qsub][nt]);
        }
        __syncthreads();   // drains prefetch (after compute) + guards buffer reuse
    }

    // ---- cross-kh reduction (reuse Kt as 16 KB float buffer) ----
    float* red = (float*)&Kt[0][0][0];   // [qh][q_local 32][d 64]
    if (kh == 1) {
#pragma unroll
        for (int qsub = 0; qsub < 2; ++qsub) {
#pragma unroll
            for (int nt = 0; nt < 4; ++nt)
#pragma unroll
                for (int r = 0; r < 4; ++r)
                    red[qh * 2048 + (qsub * 16 + quad * 4 + r) * 64 + nt * 16 + l16] =
                        o_acc[qsub][nt][r];
            if (l16 == 0)
#pragma unroll
                for (int r = 0; r < 4; ++r)
                    lbuf[qh * 32 + qsub * 16 + quad * 4 + r] = l_acc[qsub][r];
        }
    }
    __syncthreads();
    if (kh == 0) {
#pragma unroll
        for (int qsub = 0; qsub < 2; ++qsub) {
            float linv[4];
#pragma unroll
            for (int r = 0; r < 4; ++r)
                linv[r] = 1.0f / (l_acc[qsub][r] + lbuf[qh * 32 + qsub * 16 + quad * 4 + r]);
            const int s = qt * 64 + qh * 32 + qsub * 16 + quad * 4;
            float* ob = out + ((size_t)b * SEQ + s) * EMB + h * HD + l16;
#pragma unroll
            for (int nt = 0; nt < 4; ++nt)
#pragma unroll
                for (int r = 0; r < 4; ++r) {
                    const float o = o_acc[qsub][nt][r] +
                        red[qh * 2048 + (qsub * 16 + quad * 4 + r) * 64 + nt * 16 + l16];
                    ob[(size_t)r * EMB + nt * 16] = o * linv[r];
                }
        }
    }
}

extern "C" void kernel_launch(void* const* d_in, const int* in_sizes, int n_in,
                              void* d_out, int out_size, void* d_ws, size_t ws_size,
                              hipStream_t stream) {
    (void)in_sizes; (void)n_in; (void)out_size; (void)ws_size;
    const float* x  = (const float*)d_in[0];
    const float* Wq = (const float*)d_in[1];
    const float* Wk = (const float*)d_in[2];
    const float* Wv = (const float*)d_in[3];
    const float* g  = (const float*)d_in[4];
    float* out = (float*)d_out;

    const size_t per = (size_t)BAT * NH * SEQ * HD;   // 4,194,304 elems
    short* qws   = (short*)d_ws;
    short* kws   = qws + per;
    short* vperm = kws + per;                          // ws: 25.2 MB total

    // bf16 staging lives in d_out (16.8 MB; attn fully overwrites it last)
    short* xb = (short*)out;                           // 4M shorts
    short* wb = xb + (size_t)MTOT * EMB;               // 3M shorts (7M <= 8.38M cap)

    prep_kernel<<<7168, 256, 0, stream>>>(x, Wq, Wk, Wv, xb, wb);
    qkv_gemm_fast<<<dim3(MTOT / 128, NTOT / 128), 256, 0, stream>>>(
        xb, wb, qws, kws, vperm, g);
    attn_kernel<<<(SEQ / 64) * BAT * NH, 256, 0, stream>>>(qws, kws, vperm, out);
}